// Round 1
// baseline (9.702 us; speedup 1.0000x reference)
//
#include <hip/hip_runtime.h>
#include <math.h>

#define LSEQ 2048
#define NB   32
#define TPB  256   // 4 waves of 64
#define EPT  8     // elements per thread: 256*8 = 2048

// One block per batch row. Decomposition:
//   m      = max_{i<=j} (s[i]+e[j]) = max_j (prefmax_s[j] + e[j])
//   Z      = sum_{i<=j} exp(s[i]+e[j]-m) = sum_j exp(e[j]+a-m) * PS[j],
//            PS[j] = sum_{i<=j} exp(s[i]-a),  a = max_i s[i]
//   prob   = 1/Z ; argmax tiebreak = smallest flat index i*L+j (jnp.argmax).
__global__ __launch_bounds__(TPB) void span_decode_kernel(
    const float* __restrict__ start_logits,
    const float* __restrict__ end_logits,
    float* __restrict__ out)
{
    const int b    = blockIdx.x;
    const int t    = threadIdx.x;
    const int lane = t & 63;
    const int wav  = t >> 6;   // 0..3

    const float* s = start_logits + (size_t)b * LSEQ;
    const float* e = end_logits   + (size_t)b * LSEQ;

    // ---- coalesced vector loads: 8 consecutive floats per thread ----
    float4 sa = *(const float4*)(s + t * EPT);
    float4 sb = *(const float4*)(s + t * EPT + 4);
    float4 ea = *(const float4*)(e + t * EPT);
    float4 eb = *(const float4*)(e + t * EPT + 4);
    float sv[EPT] = {sa.x, sa.y, sa.z, sa.w, sb.x, sb.y, sb.z, sb.w};
    float ev[EPT] = {ea.x, ea.y, ea.z, ea.w, eb.x, eb.y, eb.z, eb.w};

    __shared__ float w_maxv[4];
    __shared__ int   w_maxi[4];
    __shared__ float w_sum[4];
    __shared__ float w_redv[4];
    __shared__ int   w_redi[4];
    __shared__ float w_reds[4];
    __shared__ float bc_m;
    __shared__ int   bc_flat;
    __shared__ float bc_a;

    // ================= Step 1: a = row max of s =================
    float lm = sv[0];
    #pragma unroll
    for (int k = 1; k < EPT; ++k) lm = fmaxf(lm, sv[k]);
    #pragma unroll
    for (int off = 32; off; off >>= 1) lm = fmaxf(lm, __shfl_xor(lm, off));
    if (lane == 0) w_redv[wav] = lm;
    __syncthreads();
    if (t == 0)
        bc_a = fmaxf(fmaxf(w_redv[0], w_redv[1]), fmaxf(w_redv[2], w_redv[3]));
    __syncthreads();
    const float a = bc_a;

    // ================= Step 2: per-thread partials over its 8 elems ========
    float pv = -INFINITY; int pi = 0; float ps = 0.0f;
    #pragma unroll
    for (int k = 0; k < EPT; ++k) {
        if (sv[k] > pv) { pv = sv[k]; pi = t * EPT + k; }   // strict >: earliest idx wins
        ps += expf(sv[k] - a);
    }

    // ---- wave-level inclusive scan (Hillis-Steele over 64 lanes) ----
    float spv = pv; int spi = pi; float sps = ps;
    #pragma unroll
    for (int off = 1; off < 64; off <<= 1) {
        float ov = __shfl_up(spv, off);
        int   oi = __shfl_up(spi, off);
        float os = __shfl_up(sps, off);
        if (lane >= off) {
            // prev segment (ov,oi) is earlier: on ties prev wins
            if (ov >= spv) { spv = ov; spi = oi; }
            sps += os;
        }
    }
    if (lane == 63) { w_maxv[wav] = spv; w_maxi[wav] = spi; w_sum[wav] = sps; }
    __syncthreads();

    // ---- wave-exclusive offsets (each thread combines earlier wave totals) ----
    float offv = -INFINITY; int offi = 0; float offs = 0.0f;
    for (int w = 0; w < wav; ++w) {
        float tv = w_maxv[w];
        if (tv > offv) { offv = tv; offi = w_maxi[w]; }   // earlier (off) wins ties
        offs += w_sum[w];
    }

    // ---- thread-exclusive prefix = wave offset (+) shifted inclusive scan ----
    float p1v = __shfl_up(spv, 1);
    int   p1i = __shfl_up(spi, 1);
    float p1s = __shfl_up(sps, 1);
    float exv = offv; int exi = offi; float exs = offs;
    if (lane > 0) {
        if (p1v > exv) { exv = p1v; exi = p1i; }          // earlier (off) wins ties
        exs += p1s;
    }

    // ================= Step 3: sweep own 8 j's; candidate max ==============
    float psk[EPT];
    float bestv = -INFINITY; int bestflat = 0;
    #pragma unroll
    for (int k = 0; k < EPT; ++k) {
        if (sv[k] > exv) { exv = sv[k]; exi = t * EPT + k; }  // strict >
        exs += expf(sv[k] - a);
        psk[k] = exs;                     // PS[j], j = t*EPT+k
        const int j = t * EPT + k;
        const float cand = exv + ev[k];   // prefmax_s[j] + e[j]
        const int flat = exi * LSEQ + j;
        if (cand > bestv || (cand == bestv && flat < bestflat)) {
            bestv = cand; bestflat = flat;
        }
    }

    // ---- block argmax reduce (value desc, flat asc tiebreak) ----
    #pragma unroll
    for (int off = 32; off; off >>= 1) {
        float ov = __shfl_xor(bestv, off);
        int   oi = __shfl_xor(bestflat, off);
        if (ov > bestv || (ov == bestv && oi < bestflat)) { bestv = ov; bestflat = oi; }
    }
    if (lane == 0) { w_redv[wav] = bestv; w_redi[wav] = bestflat; }
    __syncthreads();
    if (t == 0) {
        float mv = w_redv[0]; int mi = w_redi[0];
        for (int w = 1; w < 4; ++w) {
            if (w_redv[w] > mv || (w_redv[w] == mv && w_redi[w] < mi)) {
                mv = w_redv[w]; mi = w_redi[w];
            }
        }
        bc_m = mv; bc_flat = mi;
    }
    __syncthreads();
    const float m = bc_m;

    // ================= Step 4: Z = sum_j exp(e[j]+a-m) * PS[j] =============
    float z = 0.0f;
    #pragma unroll
    for (int k = 0; k < EPT; ++k)
        z += expf(ev[k] + a - m) * psk[k];
    #pragma unroll
    for (int off = 32; off; off >>= 1) z += __shfl_xor(z, off);
    if (lane == 0) w_reds[wav] = z;
    __syncthreads();

    if (t == 0) {
        const float Z = w_reds[0] + w_reds[1] + w_reds[2] + w_reds[3];
        const int flat = bc_flat;
        out[b]          = 1.0f / Z;                    // best_span_probs
        out[NB + b]     = (float)(flat / LSEQ);        // span_start_indices
        out[2 * NB + b] = (float)(flat % LSEQ);        // span_end_indices
    }
}

extern "C" void kernel_launch(void* const* d_in, const int* in_sizes, int n_in,
                              void* d_out, int out_size, void* d_ws, size_t ws_size,
                              hipStream_t stream) {
    const float* start_logits = (const float*)d_in[0];
    const float* end_logits   = (const float*)d_in[1];
    float* out = (float*)d_out;
    span_decode_kernel<<<NB, TPB, 0, stream>>>(start_logits, end_logits, out);
}